// Round 4
// baseline (329.046 us; speedup 1.0000x reference)
//
#include <hip/hip_runtime.h>
#include <math.h>

#define NNODES 15840
#define NEDGES 253440
#define INCH 128
#define HIDC 256
#define BGR 48
#define GNODES 330

// ---------------- LayerNorm: one wave per node row (128 feats, 2/lane) ----------------
__global__ void ln_kernel(const float* __restrict__ x, const float* __restrict__ g,
                          const float* __restrict__ b, float* __restrict__ xln) {
  int wid = (blockIdx.x * blockDim.x + threadIdx.x) >> 6;
  int lane = threadIdx.x & 63;
  if (wid >= NNODES) return;
  float2 v = *(const float2*)(x + (size_t)wid * INCH + lane * 2);
  float s = v.x + v.y;
#pragma unroll
  for (int o = 32; o > 0; o >>= 1) s += __shfl_xor(s, o);
  float mean = s * (1.0f / INCH);
  float d0 = v.x - mean, d1 = v.y - mean;
  float sq = d0 * d0 + d1 * d1;
#pragma unroll
  for (int o = 32; o > 0; o >>= 1) sq += __shfl_xor(sq, o);
  float rstd = rsqrtf(sq * (1.0f / INCH) + 1e-5f);
  float2 gg = *(const float2*)(g + lane * 2);
  float2 bb = *(const float2*)(b + lane * 2);
  float2 o2;
  o2.x = d0 * rstd * gg.x + bb.x;
  o2.y = d1 * rstd * gg.y + bb.y;
  *(float2*)(xln + (size_t)wid * INCH + lane * 2) = o2;
}

// ---------------- Q,K,V,Skip SGEMM: 128x128 tile, 8x8 quadrant micro-tile ----------------
#define GBM 128
#define GBN 128
#define GBK 32
#define KD 128
__global__ __launch_bounds__(256) void gemm_qkvs(
    const float* __restrict__ xln,
    const float* __restrict__ Wq, const float* __restrict__ bq,
    const float* __restrict__ Wk, const float* __restrict__ bk,
    const float* __restrict__ Wv, const float* __restrict__ bv,
    const float* __restrict__ Ws, const float* __restrict__ bs,
    float* __restrict__ QKVS) {
  __shared__ float As[GBK][GBM];
  __shared__ float Bs[GBK][GBN];
  int t = threadIdx.x;
  int m0 = blockIdx.x * GBM;
  int jb = blockIdx.y;            // 0..7 -> 128-col block of [Q|K|V|S]
  const float* W; const float* bias;
  switch (jb >> 1) {
    case 0:  W = Wq; bias = bq; break;
    case 1:  W = Wk; bias = bk; break;
    case 2:  W = Wv; bias = bv; break;
    default: W = Ws; bias = bs; break;
  }
  int j0 = (jb & 1) * GBN;        // row offset inside the 256-row weight matrix

  int r = t & 127;                // staging row (A: node row, B: weight row)
  int half = t >> 7;              // which 16-k chunk
  int tx = t & 15, ty = t >> 4;   // 16x16 thread grid

  int gr = m0 + r;
  bool okA = gr < NNODES;
  const float* arow = xln + (size_t)gr * KD;
  const float* brow = W + (size_t)(j0 + r) * KD;

  float acc[8][8] = {};

  for (int k0 = 0; k0 < KD; k0 += GBK) {
#pragma unroll
    for (int i = 0; i < 4; i++) {
      int lk = half * 16 + i * 4;
      int kc = k0 + lk;
      float4 av = okA ? *(const float4*)(arow + kc) : make_float4(0.f, 0.f, 0.f, 0.f);
      As[lk + 0][r] = av.x; As[lk + 1][r] = av.y;
      As[lk + 2][r] = av.z; As[lk + 3][r] = av.w;
      float4 bvv = *(const float4*)(brow + kc);
      Bs[lk + 0][r] = bvv.x; Bs[lk + 1][r] = bvv.y;
      Bs[lk + 2][r] = bvv.z; Bs[lk + 3][r] = bvv.w;
    }
    __syncthreads();
#pragma unroll 2
    for (int k = 0; k < GBK; k++) {
      float4 a0 = *(const float4*)&As[k][ty * 4];
      float4 a1 = *(const float4*)&As[k][64 + ty * 4];
      float4 b0 = *(const float4*)&Bs[k][tx * 4];
      float4 b1 = *(const float4*)&Bs[k][64 + tx * 4];
      float aa[8] = {a0.x, a0.y, a0.z, a0.w, a1.x, a1.y, a1.z, a1.w};
      float bb[8] = {b0.x, b0.y, b0.z, b0.w, b1.x, b1.y, b1.z, b1.w};
#pragma unroll
      for (int ar = 0; ar < 8; ar++)
#pragma unroll
        for (int ac = 0; ac < 8; ac++) acc[ar][ac] += aa[ar] * bb[ac];
    }
    __syncthreads();
  }

  float4 bb0 = *(const float4*)(bias + j0 + tx * 4);
  float4 bb1 = *(const float4*)(bias + j0 + 64 + tx * 4);
  int col0 = jb * 128 + tx * 4;
#pragma unroll
  for (int ar = 0; ar < 8; ar++) {
    int grow = m0 + ((ar < 4) ? (ty * 4 + ar) : (64 + ty * 4 + ar - 4));
    if (grow < NNODES) {
      float4 o0, o1;
      o0.x = acc[ar][0] + bb0.x; o0.y = acc[ar][1] + bb0.y;
      o0.z = acc[ar][2] + bb0.z; o0.w = acc[ar][3] + bb0.w;
      o1.x = acc[ar][4] + bb1.x; o1.y = acc[ar][5] + bb1.y;
      o1.z = acc[ar][6] + bb1.z; o1.w = acc[ar][7] + bb1.w;
      *(float4*)(QKVS + (size_t)grow * 1024 + col0) = o0;
      *(float4*)(QKVS + (size_t)grow * 1024 + col0 + 64) = o1;
    }
  }
}

// ---------------- CSR build ----------------
__global__ void count_kernel(const int* __restrict__ dst, int* __restrict__ deg) {
  int e = blockIdx.x * blockDim.x + threadIdx.x;
  if (e < NEDGES) atomicAdd(&deg[dst[e]], 1);
}

// 1024-thread single-block shfl scan
__global__ void scan_kernel(const int* __restrict__ deg, int* __restrict__ row_start) {
  __shared__ int wsum[16];
  __shared__ int carry_s;
  int t = threadIdx.x;
  int lane = t & 63, w = t >> 6;
  if (t == 0) carry_s = 0;
  __syncthreads();
  for (int base = 0; base < NNODES; base += 1024) {
    int i = base + t;
    int v = (i < NNODES) ? deg[i] : 0;
    int inc = v;
#pragma unroll
    for (int o = 1; o < 64; o <<= 1) {
      int nv = __shfl_up(inc, o);
      if (lane >= o) inc += nv;
    }
    if (lane == 63) wsum[w] = inc;
    __syncthreads();
    if (w == 0 && lane < 16) {
      int ws = wsum[lane];
#pragma unroll
      for (int o = 1; o < 16; o <<= 1) {
        int nv = __shfl_up(ws, o);
        if (lane >= o) ws += nv;
      }
      wsum[lane] = ws;
    }
    __syncthreads();
    int wexcl = (w > 0) ? wsum[w - 1] : 0;
    int chunk_total = wsum[15];
    int cl = carry_s;
    if (i < NNODES) row_start[i] = cl + wexcl + inc - v;
    __syncthreads();
    if (t == 0) carry_s += chunk_total;
  }
  __syncthreads();
  if (t == 0) row_start[NNODES] = carry_s;
}

__global__ void scatter_kernel(const int* __restrict__ dst, const int* __restrict__ row_start,
                               int* __restrict__ cursor, int* __restrict__ elist) {
  int e = blockIdx.x * blockDim.x + threadIdx.x;
  if (e < NEDGES) {
    int d = dst[e];
    int pos = atomicAdd(&cursor[d], 1);
    elist[row_start[d] + pos] = e;
  }
}

// ---------------- Attention: 2 waves per dst node, 8-edge batches, LDS merge ----------
// factored algebra: alpha = (q.k + (We^T q).ea)/16 ; out = (Sum p v + We Sum p ea)/z + skip
__global__ __launch_bounds__(256) void agg_kernel(
    const float* __restrict__ QKVS, const float* __restrict__ edge_attr,
    const float* __restrict__ We, const int* __restrict__ srcArr,
    const int* __restrict__ row_start, const int* __restrict__ elist,
    float* __restrict__ outb) {
  __shared__ float uni[2][2][8];     // per node-half: m, z, ea[5]
  __shared__ float4 pl[2][2][64];    // per node-half per lane: acc4
  int t = threadIdx.x;
  int w = t >> 6, lane = t & 63;
  int ln = w >> 1;                    // local node 0/1
  int h = w & 1;                      // half 0/1
  int nd = blockIdx.x * 2 + ln;       // NNODES even -> always valid

  float4 q = *(const float4*)(QKVS + (size_t)nd * 1024 + 4 * lane);

  // c5 = We^T q  (uniform), wp registers released after this scope
  float c5[5];
  {
    float wp0[5], wp1[5], wp2[5], wp3[5];
#pragma unroll
    for (int d = 0; d < 5; d++) {
      wp0[d] = We[(4 * lane + 0) * 5 + d];
      wp1[d] = We[(4 * lane + 1) * 5 + d];
      wp2[d] = We[(4 * lane + 2) * 5 + d];
      wp3[d] = We[(4 * lane + 3) * 5 + d];
    }
#pragma unroll
    for (int d = 0; d < 5; d++) {
      float s = q.x * wp0[d] + q.y * wp1[d] + q.z * wp2[d] + q.w * wp3[d];
#pragma unroll
      for (int o = 32; o > 0; o >>= 1) s += __shfl_xor(s, o);
      c5[d] = s;
    }
  }

  int beg = row_start[nd], end = row_start[nd + 1];
  float m = -1e30f, z = 0.0f;
  float ax = 0.f, ay = 0.f, az = 0.f, aw = 0.f;
  float ea[5] = {0.f, 0.f, 0.f, 0.f, 0.f};

  for (int j0 = beg + h * 8; j0 < end; j0 += 16) {
    int e_[8], s_[8];
#pragma unroll
    for (int i = 0; i < 8; i++) {
      int jj = j0 + i;
      e_[i] = elist[jj < end ? jj : j0];
    }
#pragma unroll
    for (int i = 0; i < 8; i++) s_[i] = srcArr[e_[i]];
    float4 kk[8], vv[8];
#pragma unroll
    for (int i = 0; i < 8; i++) {
      const float* bp = QKVS + (size_t)s_[i] * 1024 + 4 * lane;
      kk[i] = *(const float4*)(bp + 256);
      vv[i] = *(const float4*)(bp + 512);
    }
    float at[8][5];
#pragma unroll
    for (int i = 0; i < 8; i++) {
      const float* ap = edge_attr + (size_t)e_[i] * 5;
#pragma unroll
      for (int d = 0; d < 5; d++) at[i][d] = ap[d];
    }
    float p[8];
#pragma unroll
    for (int i = 0; i < 8; i++)
      p[i] = q.x * kk[i].x + q.y * kk[i].y + q.z * kk[i].z + q.w * kk[i].w;
#pragma unroll
    for (int o = 32; o > 0; o >>= 1) {
#pragma unroll
      for (int i = 0; i < 8; i++) p[i] += __shfl_xor(p[i], o);
    }
    float al[8];
    float bm = -1e30f;
#pragma unroll
    for (int i = 0; i < 8; i++) {
      float dt = c5[0] * at[i][0] + c5[1] * at[i][1] + c5[2] * at[i][2] +
                 c5[3] * at[i][3] + c5[4] * at[i][4];
      float a = (p[i] + dt) * 0.0625f;
      al[i] = (j0 + i < end) ? a : -1e30f;
      bm = fmaxf(bm, al[i]);
    }
    float nm = fmaxf(m, bm);
    float sc = __expf(m - nm);     // first batch: exp(-huge)=0
    float wg[8];
#pragma unroll
    for (int i = 0; i < 8; i++) wg[i] = __expf(al[i] - nm);  // masked -> 0
    float zs = 0.f, sx = 0.f, sy = 0.f, sz2 = 0.f, sw = 0.f;
    float se[5] = {0.f, 0.f, 0.f, 0.f, 0.f};
#pragma unroll
    for (int i = 0; i < 8; i++) {
      zs += wg[i];
      sx += wg[i] * vv[i].x; sy += wg[i] * vv[i].y;
      sz2 += wg[i] * vv[i].z; sw += wg[i] * vv[i].w;
#pragma unroll
      for (int d = 0; d < 5; d++) se[d] += wg[i] * at[i][d];
    }
    z = z * sc + zs;
    ax = ax * sc + sx; ay = ay * sc + sy;
    az = az * sc + sz2; aw = aw * sc + sw;
#pragma unroll
    for (int d = 0; d < 5; d++) ea[d] = ea[d] * sc + se[d];
    m = nm;
  }

  if (lane == 0) {
    uni[ln][h][0] = m; uni[ln][h][1] = z;
#pragma unroll
    for (int d = 0; d < 5; d++) uni[ln][h][2 + d] = ea[d];
  }
  pl[ln][h][lane] = make_float4(ax, ay, az, aw);
  __syncthreads();

  if (h == 0) {
    float mA = uni[ln][0][0], zA = uni[ln][0][1];
    float mB = uni[ln][1][0], zB = uni[ln][1][1];
    float M = fmaxf(mA, mB);
    float sA = __expf(mA - M), sB = __expf(mB - M);
    float zz = zA * sA + zB * sB;
    float inv = 1.0f / (zz + 1e-16f);
    float4 aA = pl[ln][0][lane];
    float4 aB = pl[ln][1][lane];
    float mx = aA.x * sA + aB.x * sB;
    float my = aA.y * sA + aB.y * sB;
    float mz = aA.z * sA + aB.z * sB;
    float mw = aA.w * sA + aB.w * sB;
    float ead[5];
#pragma unroll
    for (int d = 0; d < 5; d++)
      ead[d] = uni[ln][0][2 + d] * sA + uni[ln][1][2 + d] * sB;
    float ef0 = 0.f, ef1 = 0.f, ef2 = 0.f, ef3 = 0.f;
#pragma unroll
    for (int d = 0; d < 5; d++) {
      ef0 += We[(4 * lane + 0) * 5 + d] * ead[d];
      ef1 += We[(4 * lane + 1) * 5 + d] * ead[d];
      ef2 += We[(4 * lane + 2) * 5 + d] * ead[d];
      ef3 += We[(4 * lane + 3) * 5 + d] * ead[d];
    }
    float4 sk = *(const float4*)(QKVS + (size_t)nd * 1024 + 768 + 4 * lane);
    float4 o;
    o.x = (mx + ef0) * inv + sk.x;
    o.y = (my + ef1) * inv + sk.y;
    o.z = (mz + ef2) * inv + sk.z;
    o.w = (mw + ef3) * inv + sk.w;
    *(float4*)(outb + (size_t)nd * HIDC + 4 * lane) = o;
  }
}

// ---------------- BatchNorm statistics ----------------
__global__ void bnstat_kernel(const float* __restrict__ outb, float* __restrict__ sums,
                              float* __restrict__ sumsq) {
  int f = threadIdx.x;
  int r0 = blockIdx.x * 120;
  float s = 0.0f, sq = 0.0f;
  for (int r = 0; r < 120; r++) {
    float v = outb[(size_t)(r0 + r) * HIDC + f];
    s += v; sq += v * v;
  }
  atomicAdd(&sums[f], s);
  atomicAdd(&sumsq[f], sq);
}

// ---------------- BN-apply + ReLU + max-pool + MLP head, fused ----------------
__global__ void pool_mlp_kernel(const float* __restrict__ outb, const float* __restrict__ sums,
                                const float* __restrict__ sumsq, const float* __restrict__ bng,
                                const float* __restrict__ bnb, const float* __restrict__ W1,
                                const float* __restrict__ b1, const float* __restrict__ Wr,
                                float* __restrict__ c) {
  __shared__ float hs[HIDC];
  __shared__ float red[HIDC];
  int bt = blockIdx.x, t = threadIdx.x;
  int b = bt / 18, tt = bt % 18;
  float mean = sums[t] * (1.0f / NNODES);
  float var = sumsq[t] * (1.0f / NNODES) - mean * mean;
  float scale = bng[t] * rsqrtf(var + 1e-5f);
  float shift = bnb[t] - mean * scale;
  int base = b * GNODES + tt * 18;
  float mx = -INFINITY;
  for (int r = 0; r < 18; r++) {
    float v = outb[(size_t)(base + r) * HIDC + t];
    mx = fmaxf(mx, fmaxf(v * scale + shift, 0.0f));
  }
  hs[t] = mx;
  __syncthreads();
  const float4* hv = (const float4*)hs;
  const float4* w = (const float4*)(W1 + t * HIDC);
  float acc = b1[t];
#pragma unroll 8
  for (int i = 0; i < HIDC / 4; i++) {
    float4 xi = hv[i]; float4 ww = w[i];
    acc += xi.x * ww.x + xi.y * ww.y + xi.z * ww.z + xi.w * ww.w;
  }
  red[t] = fmaxf(acc, 0.0f) * Wr[t];
  __syncthreads();
#pragma unroll
  for (int s = 128; s > 0; s >>= 1) {
    if (t < s) red[t] += red[t + s];
    __syncthreads();
  }
  if (t == 0) atomicAdd(&c[b], red[0] * (1.0f / 18.0f));
}

__global__ void final_kernel(const float* __restrict__ c, const float* __restrict__ br,
                             float* __restrict__ out) {
  int b = threadIdx.x;
  if (b < BGR) out[b] = 1.0f / (1.0f + expf(-(c[b] + br[0])));
}

extern "C" void kernel_launch(void* const* d_in, const int* in_sizes, int n_in,
                              void* d_out, int out_size, void* d_ws, size_t ws_size,
                              hipStream_t stream) {
  const float* x   = (const float*)d_in[0];
  const int*   ei  = (const int*)d_in[1];
  const float* ea  = (const float*)d_in[2];
  const float* Wq  = (const float*)d_in[4];  const float* bq  = (const float*)d_in[5];
  const float* Wk  = (const float*)d_in[6];  const float* bk  = (const float*)d_in[7];
  const float* Wv  = (const float*)d_in[8];  const float* bv  = (const float*)d_in[9];
  const float* We  = (const float*)d_in[10];
  const float* Wsk = (const float*)d_in[11]; const float* bsk = (const float*)d_in[12];
  const float* lng = (const float*)d_in[13]; const float* lnb = (const float*)d_in[14];
  const float* bng = (const float*)d_in[15]; const float* bnb = (const float*)d_in[16];
  const float* W1  = (const float*)d_in[17]; const float* b1  = (const float*)d_in[18];
  const float* Wr  = (const float*)d_in[19]; const float* br  = (const float*)d_in[20];
  float* outp = (float*)d_out;

  const int* srcArr = ei;
  const int* dstArr = ei + NEDGES;

  char* ws = (char*)d_ws;
  size_t off = 0;
  auto alloc = [&](size_t bytes) -> void* {
    void* p = ws + off;
    off += (bytes + 255) & ~(size_t)255;
    return p;
  };
  float* xln       = (float*)alloc((size_t)NNODES * INCH * 4);
  float* QKVS      = (float*)alloc((size_t)NNODES * 1024 * 4);
  float* outb      = (float*)alloc((size_t)NNODES * HIDC * 4);
  int*   row_start = (int*)alloc((size_t)(NNODES + 1) * 4);
  int*   elist     = (int*)alloc((size_t)NEDGES * 4);
  // contiguous zero block: deg, cursor, sums, sumsq, cacc
  size_t zn = (size_t)NNODES * 2 + HIDC * 2 + BGR;
  int* zblock = (int*)alloc(zn * 4);
  int*   deg    = zblock;
  int*   cursor = zblock + NNODES;
  float* sums   = (float*)(zblock + 2 * NNODES);
  float* sumsq  = sums + HIDC;
  float* cacc   = sumsq + HIDC;

  hipMemsetAsync(zblock, 0, zn * 4, stream);

  ln_kernel<<<NNODES / 4, 256, 0, stream>>>(x, lng, lnb, xln);
  dim3 ggrid((NNODES + GBM - 1) / GBM, 8);
  gemm_qkvs<<<ggrid, 256, 0, stream>>>(xln, Wq, bq, Wk, bk, Wv, bv, Wsk, bsk, QKVS);
  count_kernel<<<NEDGES / 256, 256, 0, stream>>>(dstArr, deg);
  scan_kernel<<<1, 1024, 0, stream>>>(deg, row_start);
  scatter_kernel<<<NEDGES / 256, 256, 0, stream>>>(dstArr, row_start, cursor, elist);
  agg_kernel<<<NNODES / 2, 256, 0, stream>>>(QKVS, ea, We, srcArr, row_start, elist, outb);
  bnstat_kernel<<<132, 256, 0, stream>>>(outb, sums, sumsq);
  pool_mlp_kernel<<<BGR * 18, 256, 0, stream>>>(outb, sums, sumsq, bng, bnb, W1, b1, Wr, cacc);
  final_kernel<<<1, 64, 0, stream>>>(cacc, br, outp);
}

// Round 5
// 296.679 us; speedup vs baseline: 1.1091x; 1.1091x over previous
//
#include <hip/hip_runtime.h>
#include <math.h>

#define NNODES 15840
#define NEDGES 253440
#define INCH 128
#define HIDC 256
#define BGR 48
#define GNODES 330

__device__ inline unsigned short f2bf(float f) {
  union { float f; unsigned int u; } v; v.f = f;
  unsigned int u = v.u;
  u += 0x7fff + ((u >> 16) & 1);           // round-to-nearest-even
  return (unsigned short)(u >> 16);
}
__device__ inline float bf2f(unsigned short h) {
  union { unsigned int u; float f; } v; v.u = ((unsigned int)h) << 16;
  return v.f;
}

// ---------------- LayerNorm: one wave per node row (128 feats, 2/lane) ----------------
__global__ void ln_kernel(const float* __restrict__ x, const float* __restrict__ g,
                          const float* __restrict__ b, float* __restrict__ xln) {
  int wid = (blockIdx.x * blockDim.x + threadIdx.x) >> 6;
  int lane = threadIdx.x & 63;
  if (wid >= NNODES) return;
  float2 v = *(const float2*)(x + (size_t)wid * INCH + lane * 2);
  float s = v.x + v.y;
#pragma unroll
  for (int o = 32; o > 0; o >>= 1) s += __shfl_xor(s, o);
  float mean = s * (1.0f / INCH);
  float d0 = v.x - mean, d1 = v.y - mean;
  float sq = d0 * d0 + d1 * d1;
#pragma unroll
  for (int o = 32; o > 0; o >>= 1) sq += __shfl_xor(sq, o);
  float rstd = rsqrtf(sq * (1.0f / INCH) + 1e-5f);
  float2 gg = *(const float2*)(g + lane * 2);
  float2 bb = *(const float2*)(b + lane * 2);
  float2 o2;
  o2.x = d0 * rstd * gg.x + bb.x;
  o2.y = d1 * rstd * gg.y + bb.y;
  *(float2*)(xln + (size_t)wid * INCH + lane * 2) = o2;
}

// ---------------- Q,K,V,Skip SGEMM: 128x128 tile; Q,S -> fp32 QS; K,V -> bf16 KV ------
#define GBM 128
#define GBN 128
#define GBK 32
#define KD 128
__global__ __launch_bounds__(256) void gemm_qkvs(
    const float* __restrict__ xln,
    const float* __restrict__ Wq, const float* __restrict__ bq,
    const float* __restrict__ Wk, const float* __restrict__ bk,
    const float* __restrict__ Wv, const float* __restrict__ bv,
    const float* __restrict__ Ws, const float* __restrict__ bs,
    float* __restrict__ QS, unsigned short* __restrict__ KV) {
  __shared__ float As[GBK][GBM];
  __shared__ float Bs[GBK][GBN];
  int t = threadIdx.x;
  int m0 = blockIdx.x * GBM;
  int jb = blockIdx.y;            // 0..7 -> 128-col block of [Q|K|V|S]
  int mat = jb >> 1;
  const float* W; const float* bias;
  switch (mat) {
    case 0:  W = Wq; bias = bq; break;
    case 1:  W = Wk; bias = bk; break;
    case 2:  W = Wv; bias = bv; break;
    default: W = Ws; bias = bs; break;
  }
  int j0 = (jb & 1) * GBN;        // col offset inside the 256-col output of this matrix

  int r = t & 127;
  int half = t >> 7;
  int tx = t & 15, ty = t >> 4;

  int gr = m0 + r;
  bool okA = gr < NNODES;
  const float* arow = xln + (size_t)gr * KD;
  const float* brow = W + (size_t)(j0 + r) * KD;

  float acc[8][8] = {};

  for (int k0 = 0; k0 < KD; k0 += GBK) {
#pragma unroll
    for (int i = 0; i < 4; i++) {
      int lk = half * 16 + i * 4;
      int kc = k0 + lk;
      float4 av = okA ? *(const float4*)(arow + kc) : make_float4(0.f, 0.f, 0.f, 0.f);
      As[lk + 0][r] = av.x; As[lk + 1][r] = av.y;
      As[lk + 2][r] = av.z; As[lk + 3][r] = av.w;
      float4 bvv = *(const float4*)(brow + kc);
      Bs[lk + 0][r] = bvv.x; Bs[lk + 1][r] = bvv.y;
      Bs[lk + 2][r] = bvv.z; Bs[lk + 3][r] = bvv.w;
    }
    __syncthreads();
#pragma unroll 2
    for (int k = 0; k < GBK; k++) {
      float4 a0 = *(const float4*)&As[k][ty * 4];
      float4 a1 = *(const float4*)&As[k][64 + ty * 4];
      float4 b0 = *(const float4*)&Bs[k][tx * 4];
      float4 b1 = *(const float4*)&Bs[k][64 + tx * 4];
      float aa[8] = {a0.x, a0.y, a0.z, a0.w, a1.x, a1.y, a1.z, a1.w};
      float bb[8] = {b0.x, b0.y, b0.z, b0.w, b1.x, b1.y, b1.z, b1.w};
#pragma unroll
      for (int ar = 0; ar < 8; ar++)
#pragma unroll
        for (int ac = 0; ac < 8; ac++) acc[ar][ac] += aa[ar] * bb[ac];
    }
    __syncthreads();
  }

  float4 bb0 = *(const float4*)(bias + j0 + tx * 4);
  float4 bb1 = *(const float4*)(bias + j0 + 64 + tx * 4);
  int sec = (mat == 0 || mat == 1) ? 0 : 256;     // Q,K in first half; V,S in second
  bool isF32 = (mat == 0 || mat == 3);            // Q,S fp32; K,V bf16
  int col0 = sec + j0 + tx * 4;
#pragma unroll
  for (int ar = 0; ar < 8; ar++) {
    int grow = m0 + ((ar < 4) ? (ty * 4 + ar) : (64 + ty * 4 + ar - 4));
    if (grow < NNODES) {
      float4 o0, o1;
      o0.x = acc[ar][0] + bb0.x; o0.y = acc[ar][1] + bb0.y;
      o0.z = acc[ar][2] + bb0.z; o0.w = acc[ar][3] + bb0.w;
      o1.x = acc[ar][4] + bb1.x; o1.y = acc[ar][5] + bb1.y;
      o1.z = acc[ar][6] + bb1.z; o1.w = acc[ar][7] + bb1.w;
      if (isF32) {
        *(float4*)(QS + (size_t)grow * 512 + col0) = o0;
        *(float4*)(QS + (size_t)grow * 512 + col0 + 64) = o1;
      } else {
        ushort4 h0, h1;
        h0.x = f2bf(o0.x); h0.y = f2bf(o0.y); h0.z = f2bf(o0.z); h0.w = f2bf(o0.w);
        h1.x = f2bf(o1.x); h1.y = f2bf(o1.y); h1.z = f2bf(o1.z); h1.w = f2bf(o1.w);
        *(ushort4*)(KV + (size_t)grow * 512 + col0) = h0;
        *(ushort4*)(KV + (size_t)grow * 512 + col0 + 64) = h1;
      }
    }
  }
}

// ---------------- CSR build ----------------
__global__ void count_kernel(const int* __restrict__ dst, int* __restrict__ deg) {
  int e = blockIdx.x * blockDim.x + threadIdx.x;
  if (e < NEDGES) atomicAdd(&deg[dst[e]], 1);
}

// 1024-thread single-block shfl scan
__global__ void scan_kernel(const int* __restrict__ deg, int* __restrict__ row_start) {
  __shared__ int wsum[16];
  __shared__ int carry_s;
  int t = threadIdx.x;
  int lane = t & 63, w = t >> 6;
  if (t == 0) carry_s = 0;
  __syncthreads();
  for (int base = 0; base < NNODES; base += 1024) {
    int i = base + t;
    int v = (i < NNODES) ? deg[i] : 0;
    int inc = v;
#pragma unroll
    for (int o = 1; o < 64; o <<= 1) {
      int nv = __shfl_up(inc, o);
      if (lane >= o) inc += nv;
    }
    if (lane == 63) wsum[w] = inc;
    __syncthreads();
    if (w == 0 && lane < 16) {
      int ws = wsum[lane];
#pragma unroll
      for (int o = 1; o < 16; o <<= 1) {
        int nv = __shfl_up(ws, o);
        if (lane >= o) ws += nv;
      }
      wsum[lane] = ws;
    }
    __syncthreads();
    int wexcl = (w > 0) ? wsum[w - 1] : 0;
    int chunk_total = wsum[15];
    int cl = carry_s;
    if (i < NNODES) row_start[i] = cl + wexcl + inc - v;
    __syncthreads();
    if (t == 0) carry_s += chunk_total;
  }
  __syncthreads();
  if (t == 0) row_start[NNODES] = carry_s;
}

// permute src and edge_attr into CSR (dst-grouped) order
__global__ void scatter_kernel(const int* __restrict__ src, const int* __restrict__ dst,
                               const int* __restrict__ row_start, int* __restrict__ cursor,
                               const float* __restrict__ ea, int* __restrict__ src_perm,
                               float* __restrict__ ea_perm) {
  int e = blockIdx.x * blockDim.x + threadIdx.x;
  if (e < NEDGES) {
    int d = dst[e];
    int pos = row_start[d] + atomicAdd(&cursor[d], 1);
    src_perm[pos] = src[e];
    const float* ap = ea + (size_t)e * 5;
    float* op = ea_perm + (size_t)pos * 5;
#pragma unroll
    for (int i = 0; i < 5; i++) op[i] = ap[i];
  }
}

// ---------------- Attention: one wave/dst, bf16 KV gather, 4-edge batches -------------
__global__ __launch_bounds__(256) void agg_kernel(
    const float* __restrict__ QS, const unsigned short* __restrict__ KV,
    const float* __restrict__ ea_perm, const float* __restrict__ We,
    const int* __restrict__ src_perm, const int* __restrict__ row_start,
    float* __restrict__ outb) {
  int t = threadIdx.x;
  int nd = blockIdx.x * 4 + (t >> 6);
  int lane = t & 63;
  if (nd >= NNODES) return;

  float4 q = *(const float4*)(QS + (size_t)nd * 512 + 4 * lane);

  // c5 = We^T q  (uniform across wave)
  float c5[5];
  {
    float wp0[5], wp1[5], wp2[5], wp3[5];
#pragma unroll
    for (int d = 0; d < 5; d++) {
      wp0[d] = We[(4 * lane + 0) * 5 + d];
      wp1[d] = We[(4 * lane + 1) * 5 + d];
      wp2[d] = We[(4 * lane + 2) * 5 + d];
      wp3[d] = We[(4 * lane + 3) * 5 + d];
    }
#pragma unroll
    for (int d = 0; d < 5; d++) {
      float s = q.x * wp0[d] + q.y * wp1[d] + q.z * wp2[d] + q.w * wp3[d];
#pragma unroll
      for (int o = 32; o > 0; o >>= 1) s += __shfl_xor(s, o);
      c5[d] = s;
    }
  }

  int beg = row_start[nd], end = row_start[nd + 1];
  float m = -INFINITY, z = 0.0f;
  float ax = 0.f, ay = 0.f, az = 0.f, aw = 0.f;
  float ea_acc[5] = {0.f, 0.f, 0.f, 0.f, 0.f};

  int j = beg;
  for (; j + 4 <= end; j += 4) {
    int s0 = src_perm[j], s1 = src_perm[j + 1], s2 = src_perm[j + 2], s3 = src_perm[j + 3];
    const unsigned short* b0 = KV + (size_t)s0 * 512 + 4 * lane;
    const unsigned short* b1 = KV + (size_t)s1 * 512 + 4 * lane;
    const unsigned short* b2 = KV + (size_t)s2 * 512 + 4 * lane;
    const unsigned short* b3 = KV + (size_t)s3 * 512 + 4 * lane;
    ushort4 hk0 = *(const ushort4*)b0;
    ushort4 hk1 = *(const ushort4*)b1;
    ushort4 hk2 = *(const ushort4*)b2;
    ushort4 hk3 = *(const ushort4*)b3;
    ushort4 hv0 = *(const ushort4*)(b0 + 256);
    ushort4 hv1 = *(const ushort4*)(b1 + 256);
    ushort4 hv2 = *(const ushort4*)(b2 + 256);
    ushort4 hv3 = *(const ushort4*)(b3 + 256);
    float eat[4][5];
    {
      const float* ap = ea_perm + (size_t)j * 5;
#pragma unroll
      for (int i = 0; i < 4; i++)
#pragma unroll
        for (int d = 0; d < 5; d++) eat[i][d] = ap[i * 5 + d];
    }
    float p0 = q.x * bf2f(hk0.x) + q.y * bf2f(hk0.y) + q.z * bf2f(hk0.z) + q.w * bf2f(hk0.w);
    float p1 = q.x * bf2f(hk1.x) + q.y * bf2f(hk1.y) + q.z * bf2f(hk1.z) + q.w * bf2f(hk1.w);
    float p2 = q.x * bf2f(hk2.x) + q.y * bf2f(hk2.y) + q.z * bf2f(hk2.z) + q.w * bf2f(hk2.w);
    float p3 = q.x * bf2f(hk3.x) + q.y * bf2f(hk3.y) + q.z * bf2f(hk3.z) + q.w * bf2f(hk3.w);
#pragma unroll
    for (int o = 32; o > 0; o >>= 1) {
      p0 += __shfl_xor(p0, o); p1 += __shfl_xor(p1, o);
      p2 += __shfl_xor(p2, o); p3 += __shfl_xor(p3, o);
    }
    float dt0 = 0.f, dt1 = 0.f, dt2 = 0.f, dt3 = 0.f;
#pragma unroll
    for (int d = 0; d < 5; d++) {
      dt0 += c5[d] * eat[0][d]; dt1 += c5[d] * eat[1][d];
      dt2 += c5[d] * eat[2][d]; dt3 += c5[d] * eat[3][d];
    }
    float al0 = (p0 + dt0) * 0.0625f, al1 = (p1 + dt1) * 0.0625f;
    float al2 = (p2 + dt2) * 0.0625f, al3 = (p3 + dt3) * 0.0625f;
    float bm = fmaxf(fmaxf(al0, al1), fmaxf(al2, al3));
    float nm = fmaxf(m, bm);
    float sc = __expf(m - nm);
    float w0 = __expf(al0 - nm), w1 = __expf(al1 - nm);
    float w2 = __expf(al2 - nm), w3 = __expf(al3 - nm);
    z = z * sc + (w0 + w1 + w2 + w3);
    ax = ax * sc + w0 * bf2f(hv0.x) + w1 * bf2f(hv1.x) + w2 * bf2f(hv2.x) + w3 * bf2f(hv3.x);
    ay = ay * sc + w0 * bf2f(hv0.y) + w1 * bf2f(hv1.y) + w2 * bf2f(hv2.y) + w3 * bf2f(hv3.y);
    az = az * sc + w0 * bf2f(hv0.z) + w1 * bf2f(hv1.z) + w2 * bf2f(hv2.z) + w3 * bf2f(hv3.z);
    aw = aw * sc + w0 * bf2f(hv0.w) + w1 * bf2f(hv1.w) + w2 * bf2f(hv2.w) + w3 * bf2f(hv3.w);
#pragma unroll
    for (int d = 0; d < 5; d++)
      ea_acc[d] = ea_acc[d] * sc + w0 * eat[0][d] + w1 * eat[1][d] + w2 * eat[2][d] + w3 * eat[3][d];
    m = nm;
  }
  for (; j < end; j++) {
    int s = src_perm[j];
    const unsigned short* bp = KV + (size_t)s * 512 + 4 * lane;
    ushort4 hk = *(const ushort4*)bp;
    ushort4 hv = *(const ushort4*)(bp + 256);
    float eat[5];
    const float* ap = ea_perm + (size_t)j * 5;
#pragma unroll
    for (int d = 0; d < 5; d++) eat[d] = ap[d];
    float p = q.x * bf2f(hk.x) + q.y * bf2f(hk.y) + q.z * bf2f(hk.z) + q.w * bf2f(hk.w);
#pragma unroll
    for (int o = 32; o > 0; o >>= 1) p += __shfl_xor(p, o);
    float dt = 0.f;
#pragma unroll
    for (int d = 0; d < 5; d++) dt += c5[d] * eat[d];
    float al = (p + dt) * 0.0625f;
    float nm = fmaxf(m, al);
    float sc = __expf(m - nm);
    float w = __expf(al - nm);
    z = z * sc + w;
    ax = ax * sc + w * bf2f(hv.x); ay = ay * sc + w * bf2f(hv.y);
    az = az * sc + w * bf2f(hv.z); aw = aw * sc + w * bf2f(hv.w);
#pragma unroll
    for (int d = 0; d < 5; d++) ea_acc[d] = ea_acc[d] * sc + w * eat[d];
    m = nm;
  }

  float inv = 1.0f / (z + 1e-16f);
  float4 sk = *(const float4*)(QS + (size_t)nd * 512 + 256 + 4 * lane);
  float efx = 0.f, efy = 0.f, efz = 0.f, efw = 0.f;
#pragma unroll
  for (int d = 0; d < 5; d++) {
    float ead = ea_acc[d];
    efx += We[(4 * lane + 0) * 5 + d] * ead;
    efy += We[(4 * lane + 1) * 5 + d] * ead;
    efz += We[(4 * lane + 2) * 5 + d] * ead;
    efw += We[(4 * lane + 3) * 5 + d] * ead;
  }
  float4 o;
  o.x = (ax + efx) * inv + sk.x;
  o.y = (ay + efy) * inv + sk.y;
  o.z = (az + efz) * inv + sk.z;
  o.w = (aw + efw) * inv + sk.w;
  *(float4*)(outb + (size_t)nd * HIDC + 4 * lane) = o;
}

// ---------------- BatchNorm statistics ----------------
__global__ void bnstat_kernel(const float* __restrict__ outb, float* __restrict__ sums,
                              float* __restrict__ sumsq) {
  int f = threadIdx.x;
  int r0 = blockIdx.x * 120;
  float s = 0.0f, sq = 0.0f;
  for (int r = 0; r < 120; r++) {
    float v = outb[(size_t)(r0 + r) * HIDC + f];
    s += v; sq += v * v;
  }
  atomicAdd(&sums[f], s);
  atomicAdd(&sumsq[f], sq);
}

// ---------------- BN-apply + ReLU + max-pool + MLP head, fused ----------------
__global__ void pool_mlp_kernel(const float* __restrict__ outb, const float* __restrict__ sums,
                                const float* __restrict__ sumsq, const float* __restrict__ bng,
                                const float* __restrict__ bnb, const float* __restrict__ W1,
                                const float* __restrict__ b1, const float* __restrict__ Wr,
                                float* __restrict__ c) {
  __shared__ float hs[HIDC];
  __shared__ float red[HIDC];
  int bt = blockIdx.x, t = threadIdx.x;
  int b = bt / 18, tt = bt % 18;
  float mean = sums[t] * (1.0f / NNODES);
  float var = sumsq[t] * (1.0f / NNODES) - mean * mean;
  float scale = bng[t] * rsqrtf(var + 1e-5f);
  float shift = bnb[t] - mean * scale;
  int base = b * GNODES + tt * 18;
  float mx = -INFINITY;
  for (int r = 0; r < 18; r++) {
    float v = outb[(size_t)(base + r) * HIDC + t];
    mx = fmaxf(mx, fmaxf(v * scale + shift, 0.0f));
  }
  hs[t] = mx;
  __syncthreads();
  const float4* hv = (const float4*)hs;
  const float4* w = (const float4*)(W1 + t * HIDC);
  float acc = b1[t];
#pragma unroll 8
  for (int i = 0; i < HIDC / 4; i++) {
    float4 xi = hv[i]; float4 ww = w[i];
    acc += xi.x * ww.x + xi.y * ww.y + xi.z * ww.z + xi.w * ww.w;
  }
  red[t] = fmaxf(acc, 0.0f) * Wr[t];
  __syncthreads();
#pragma unroll
  for (int s = 128; s > 0; s >>= 1) {
    if (t < s) red[t] += red[t + s];
    __syncthreads();
  }
  if (t == 0) atomicAdd(&c[b], red[0] * (1.0f / 18.0f));
}

__global__ void final_kernel(const float* __restrict__ c, const float* __restrict__ br,
                             float* __restrict__ out) {
  int b = threadIdx.x;
  if (b < BGR) out[b] = 1.0f / (1.0f + expf(-(c[b] + br[0])));
}

extern "C" void kernel_launch(void* const* d_in, const int* in_sizes, int n_in,
                              void* d_out, int out_size, void* d_ws, size_t ws_size,
                              hipStream_t stream) {
  const float* x   = (const float*)d_in[0];
  const int*   ei  = (const int*)d_in[1];
  const float* ea  = (const float*)d_in[2];
  const float* Wq  = (const float*)d_in[4];  const float* bq  = (const float*)d_in[5];
  const float* Wk  = (const float*)d_in[6];  const float* bk  = (const float*)d_in[7];
  const float* Wv  = (const float*)d_in[8];  const float* bv  = (const float*)d_in[9];
  const float* We  = (const float*)d_in[10];
  const float* Wsk = (const float*)d_in[11]; const float* bsk = (const float*)d_in[12];
  const float* lng = (const float*)d_in[13]; const float* lnb = (const float*)d_in[14];
  const float* bng = (const float*)d_in[15]; const float* bnb = (const float*)d_in[16];
  const float* W1  = (const float*)d_in[17]; const float* b1  = (const float*)d_in[18];
  const float* Wr  = (const float*)d_in[19]; const float* br  = (const float*)d_in[20];
  float* outp = (float*)d_out;

  const int* srcArr = ei;
  const int* dstArr = ei + NEDGES;

  char* ws = (char*)d_ws;
  size_t off = 0;
  auto alloc = [&](size_t bytes) -> void* {
    void* p = ws + off;
    off += (bytes + 255) & ~(size_t)255;
    return p;
  };
  float*          xln       = (float*)alloc((size_t)NNODES * INCH * 4);
  float*          QS        = (float*)alloc((size_t)NNODES * 512 * 4);
  unsigned short* KV        = (unsigned short*)alloc((size_t)NNODES * 512 * 2);
  float*          outb      = (float*)alloc((size_t)NNODES * HIDC * 4);
  int*            row_start = (int*)alloc((size_t)(NNODES + 1) * 4);
  int*            src_perm  = (int*)alloc((size_t)NEDGES * 4);
  float*          ea_perm   = (float*)alloc((size_t)NEDGES * 5 * 4);
  size_t zn = (size_t)NNODES * 2 + HIDC * 2 + BGR;
  int* zblock = (int*)alloc(zn * 4);
  int*   deg    = zblock;
  int*   cursor = zblock + NNODES;
  float* sums   = (float*)(zblock + 2 * NNODES);
  float* sumsq  = sums + HIDC;
  float* cacc   = sumsq + HIDC;

  hipMemsetAsync(zblock, 0, zn * 4, stream);

  ln_kernel<<<NNODES / 4, 256, 0, stream>>>(x, lng, lnb, xln);
  dim3 ggrid((NNODES + GBM - 1) / GBM, 8);
  gemm_qkvs<<<ggrid, 256, 0, stream>>>(xln, Wq, bq, Wk, bk, Wv, bv, Wsk, bsk, QS, KV);
  count_kernel<<<NEDGES / 256, 256, 0, stream>>>(dstArr, deg);
  scan_kernel<<<1, 1024, 0, stream>>>(deg, row_start);
  scatter_kernel<<<NEDGES / 256, 256, 0, stream>>>(srcArr, dstArr, row_start, cursor, ea,
                                                   src_perm, ea_perm);
  agg_kernel<<<NNODES / 4, 256, 0, stream>>>(QS, KV, ea_perm, We, src_perm, row_start, outb);
  bnstat_kernel<<<132, 256, 0, stream>>>(outb, sums, sumsq);
  pool_mlp_kernel<<<BGR * 18, 256, 0, stream>>>(outb, sums, sumsq, bng, bnb, W1, b1, Wr, cacc);
  final_kernel<<<1, 64, 0, stream>>>(cacc, br, outp);
}